// Round 7
// baseline (551.463 us; speedup 1.0000x reference)
//
#include <hip/hip_runtime.h>

#define B_ 4
#define C_ 512
#define CI_ 256
#define N_ 4096
#define SCALE_PAM 0.04419417382415922f  // 1/sqrt(512)
#define SCALE_CAM (1.0f/64.0f)          // 1/sqrt(4096)
#define SHIFT_PAM 8.0f

typedef float v4f __attribute__((ext_vector_type(4)));
typedef short v8s __attribute__((ext_vector_type(8)));

__device__ __forceinline__ unsigned short f2bf(float f) {
  unsigned int u = __float_as_uint(f);
  u = (u + 0x7FFFu + ((u >> 16) & 1u)) >> 16;
  return (unsigned short)u;
}
__device__ __forceinline__ float bf2f(unsigned short s) {
  return __uint_as_float(((unsigned int)s) << 16);
}
__device__ __forceinline__ v8s ld8(const unsigned short* p) {
  v8s r; *(int4*)&r = *(const int4*)p; return r;
}
__device__ __forceinline__ v4f mfma16(v8s a, v8s b, v4f c) {
  return __builtin_amdgcn_mfma_f32_16x16x32_bf16(a, b, c, 0, 0, 0);
}
// PK layout: off(r,k) = ((r>>4)*(K>>5) + (k>>5))*512 + (r&15)*32 + (k&31)  [shorts]
// Wave frag load: base + lanelin, lanelin=(lane&15)*32+(lane>>4)*8 -> contiguous 1KB.
// MFMA use: D row = A-operand row, D col = B-operand row (both PK frags).

// ---------------------------------------------------------------------------
// K_zl: zero l_g (B*N fp32 = 64 KB).
// ---------------------------------------------------------------------------
__global__ __launch_bounds__(256) void k_zl(float* __restrict__ p) {
  size_t i = ((size_t)blockIdx.x * 256 + threadIdx.x) * 4;
  *(float4*)(p + i) = (float4){0.f, 0.f, 0.f, 0.f};
}

// ---------------------------------------------------------------------------
// K_wb: wq/wk/wv fp32 -> w_pk PK(1024,512).
// ---------------------------------------------------------------------------
__global__ __launch_bounds__(256) void k_wb(const float* __restrict__ wq,
                                            const float* __restrict__ wk,
                                            const float* __restrict__ wv,
                                            unsigned short* __restrict__ w_pk) {
  int u = blockIdx.x * 256 + threadIdx.x;
  int blk = u >> 6, wi = (u & 63) * 8;
  int r = (blk >> 4) * 16 + (wi >> 5);
  int k = (blk & 15) * 32 + (wi & 31);
  const float* src = (r < 256) ? &wq[r * 512 + k]
                   : (r < 512) ? &wk[(r - 256) * 512 + k]
                               : &wv[(r - 512) * 512 + k];
  float4 f0 = *(const float4*)src, f1 = *(const float4*)(src + 4);
  ushort4 o0 = { f2bf(f0.x), f2bf(f0.y), f2bf(f0.z), f2bf(f0.w) };
  ushort4 o1 = { f2bf(f1.x), f2bf(f1.y), f2bf(f1.z), f2bf(f1.w) };
  *(ushort4*)&w_pk[u * 8] = o0;
  *(ushort4*)&w_pk[u * 8 + 4] = o1;
}

// ---------------------------------------------------------------------------
// K_xT: x fp32 [b][c][n] -> x_pk PK(4096,512) per batch (rows n, cols c).
// ---------------------------------------------------------------------------
__global__ __launch_bounds__(256) void k_xT(const float* __restrict__ x,
                                            unsigned short* __restrict__ x_pk) {
  const int b = blockIdx.z, c0 = blockIdx.y * 64, n0 = blockIdx.x * 64;
  const int t = threadIdx.x;
  __shared__ unsigned short ts[64 * 72];  // [n][c]
  const int cl = t >> 2, nseg = (t & 3) * 16;
  const float* xr = x + ((size_t)b * C_ + c0 + cl) * N_ + n0 + nseg;
#pragma unroll
  for (int k = 0; k < 4; ++k) {
    float4 f = *(const float4*)(xr + k * 4);
    ts[(nseg + k * 4 + 0) * 72 + cl] = f2bf(f.x);
    ts[(nseg + k * 4 + 1) * 72 + cl] = f2bf(f.y);
    ts[(nseg + k * 4 + 2) * 72 + cl] = f2bf(f.z);
    ts[(nseg + k * 4 + 3) * 72 + cl] = f2bf(f.w);
  }
  __syncthreads();
  unsigned short* dst = x_pk + (size_t)b * N_ * C_;
#pragma unroll
  for (int u = t; u < 512; u += 256) {
    int blk = u >> 6, wi = (u & 63) * 8;
    int rl = (blk >> 1) * 16 + (wi >> 5);
    int kl = (blk & 1) * 32 + (wi & 31);
    int gr = n0 + rl, gk = c0 + kl;
    size_t go = ((size_t)(gr >> 4) * 16 + (gk >> 5)) * 512 + (gr & 15) * 32 + (gk & 31);
    *(int4*)&dst[go] = *(int4*)&ts[rl * 72 + kl];
  }
}

// ---------------------------------------------------------------------------
// K_qkv: y[o][n] = sum_c W[o][c] x[n][c] + b.  128o x 128n tile, 512 thr.
// ---------------------------------------------------------------------------
__global__ __launch_bounds__(512) void k_qkv(
    const unsigned short* __restrict__ w_pk, const unsigned short* __restrict__ x_pk,
    const float* __restrict__ bq, const float* __restrict__ bk, const float* __restrict__ bv,
    unsigned short* __restrict__ q_pk, unsigned short* __restrict__ k_pk,
    unsigned short* __restrict__ v_pk) {
  const int b = blockIdx.z, o0 = blockIdx.y * 128, n0 = blockIdx.x * 128;
  const int t = threadIdx.x, wave = t >> 6, lane = t & 63;
  const int la = lane & 15, quad = lane >> 4;
  const int ow = wave & 1, nw = wave >> 1;
  const int lanelin = la * 32 + quad * 8;
  const unsigned short* xpb = x_pk + (size_t)b * N_ * C_;
  __shared__ unsigned short tp[128 * 136];

  v4f acc[4][2];
#pragma unroll
  for (int i = 0; i < 4; ++i)
#pragma unroll
    for (int j = 0; j < 2; ++j) acc[i][j] = (v4f){0.f, 0.f, 0.f, 0.f};

  const int ar16 = (o0 + ow * 64) >> 4;
  const int br16 = (n0 + nw * 32) >> 4;
#pragma unroll 4
  for (int s = 0; s < 16; ++s) {
    v8s b0 = ld8(&xpb[((size_t)(br16 + 0) * 16 + s) * 512 + lanelin]);
    v8s b1 = ld8(&xpb[((size_t)(br16 + 1) * 16 + s) * 512 + lanelin]);
#pragma unroll
    for (int oi = 0; oi < 4; ++oi) {
      v8s a = ld8(&w_pk[((size_t)(ar16 + oi) * 16 + s) * 512 + lanelin]);
      acc[oi][0] = mfma16(a, b0, acc[oi][0]);
      acc[oi][1] = mfma16(a, b1, acc[oi][1]);
    }
  }

  if (o0 >= 512) {
#pragma unroll
    for (int oi = 0; oi < 4; ++oi)
#pragma unroll
      for (int nj = 0; nj < 2; ++nj)
#pragma unroll
        for (int r = 0; r < 4; ++r) {
          int cl = ow * 64 + oi * 16 + quad * 4 + r;
          int nl = nw * 32 + nj * 16 + la;
          tp[cl * 136 + nl] = f2bf(acc[oi][nj][r] + bv[o0 - 512 + cl]);
        }
    __syncthreads();
    unsigned short* dst = v_pk + (size_t)b * C_ * N_;
#pragma unroll
    for (int u = t; u < 2048; u += 512) {
      int blk = u >> 6, wi = (u & 63) * 8;
      int rl = (blk >> 2) * 16 + (wi >> 5);
      int kl = (blk & 3) * 32 + (wi & 31);
      int gr = (o0 - 512) + rl, gk = n0 + kl;
      size_t go = ((size_t)(gr >> 4) * 128 + (gk >> 5)) * 512 + (gr & 15) * 32 + (gk & 31);
      *(int4*)&dst[go] = *(int4*)&tp[rl * 136 + kl];
    }
  } else {
    const float* bias = (o0 < 256) ? bq : bk;
#pragma unroll
    for (int oi = 0; oi < 4; ++oi)
#pragma unroll
      for (int nj = 0; nj < 2; ++nj)
#pragma unroll
        for (int r = 0; r < 4; ++r) {
          int ol = ow * 64 + oi * 16 + quad * 4 + r;
          int nl = nw * 32 + nj * 16 + la;
          tp[nl * 136 + ol] = f2bf(acc[oi][nj][r] + bias[(o0 & 255) + ol]);
        }
    __syncthreads();
    unsigned short* dst = ((o0 < 256) ? q_pk : k_pk) + (size_t)b * N_ * CI_;
#pragma unroll
    for (int u = t; u < 2048; u += 512) {
      int blk = u >> 6, wi = (u & 63) * 8;
      int rl = (blk >> 2) * 16 + (wi >> 5);
      int kl = (blk & 3) * 32 + (wi & 31);
      int gr = n0 + rl, gk = (o0 & 255) + kl;
      size_t go = ((size_t)(gr >> 4) * 8 + (gk >> 5)) * 512 + (gr & 15) * 32 + (gk & 31);
      *(int4*)&dst[go] = *(int4*)&tp[rl * 136 + kl];
    }
  }
}

// ---------------------------------------------------------------------------
// K_s: P = exp(scale*Q^T K - shift) for a 128i x 128j tile; also l row-sums.
// A = q_pk rows i (K=256), B = k_pk rows j. No inner barrier.
// P -> p_pk PK(4096 i, 4096 j), per-2-batch region (z = local batch).
// l -> global atomicAdd into l_g[b][i].
// ---------------------------------------------------------------------------
__global__ __launch_bounds__(512) void k_s(
    const unsigned short* __restrict__ q_pk, const unsigned short* __restrict__ k_pk,
    unsigned short* __restrict__ p_pk, float* __restrict__ l_g, int bbase) {
  const int z = blockIdx.z, b = bbase + z;
  const int i0 = blockIdx.y * 128, j0 = blockIdx.x * 128;
  const int t = threadIdx.x, wave = t >> 6, lane = t & 63;
  const int la = lane & 15, quad = lane >> 4;
  const int iw = wave & 1, jw = wave >> 1;
  const int lanelin = la * 32 + quad * 8;
  __shared__ unsigned short ts[128 * 136];
  __shared__ float l_t[128];
  if (t < 128) l_t[t] = 0.f;
  __syncthreads();

  const unsigned short* qb = q_pk + (size_t)b * N_ * CI_;
  const unsigned short* kb = k_pk + (size_t)b * N_ * CI_;

  v4f acc[4][2];
#pragma unroll
  for (int i = 0; i < 4; ++i)
#pragma unroll
    for (int j = 0; j < 2; ++j) acc[i][j] = (v4f){0.f, 0.f, 0.f, 0.f};

  const int ar16 = (i0 + iw * 64) >> 4;       // q_pk row-blocks (K=256 -> 8 k32)
  const int br16 = (j0 + jw * 32) >> 4;       // k_pk row-blocks
#pragma unroll
  for (int s = 0; s < 8; ++s) {
    v8s b0 = ld8(&kb[((size_t)(br16 + 0) * 8 + s) * 512 + lanelin]);
    v8s b1 = ld8(&kb[((size_t)(br16 + 1) * 8 + s) * 512 + lanelin]);
#pragma unroll
    for (int ci = 0; ci < 4; ++ci) {
      v8s a = ld8(&qb[((size_t)(ar16 + ci) * 8 + s) * 512 + lanelin]);
      acc[ci][0] = mfma16(a, b0, acc[ci][0]);
      acc[ci][1] = mfma16(a, b1, acc[ci][1]);
    }
  }

  // epilogue: p = exp(scale*s - shift); stage tile; accumulate l
  float lsum[4][4];
#pragma unroll
  for (int ci = 0; ci < 4; ++ci)
#pragma unroll
    for (int r = 0; r < 4; ++r) lsum[ci][r] = 0.f;
#pragma unroll
  for (int ci = 0; ci < 4; ++ci)
#pragma unroll
    for (int nj = 0; nj < 2; ++nj)
#pragma unroll
      for (int r = 0; r < 4; ++r) {
        float p = __expf(acc[ci][nj][r] * SCALE_PAM - SHIFT_PAM);
        int rl = iw * 64 + ci * 16 + quad * 4 + r;
        int cl = jw * 32 + nj * 16 + la;
        ts[rl * 136 + cl] = f2bf(p);
        lsum[ci][r] += p;
      }
#pragma unroll
  for (int ci = 0; ci < 4; ++ci)
#pragma unroll
    for (int r = 0; r < 4; ++r) {
      float v = lsum[ci][r];
      v += __shfl_xor(v, 1); v += __shfl_xor(v, 2);
      v += __shfl_xor(v, 4); v += __shfl_xor(v, 8);
      if (la == 0) atomicAdd(&l_t[iw * 64 + ci * 16 + quad * 4 + r], v);
    }
  __syncthreads();
  if (t < 128) atomicAdd(&l_g[(size_t)b * N_ + i0 + t], l_t[t]);

  unsigned short* pb = p_pk + (size_t)z * N_ * N_;
#pragma unroll
  for (int u = t; u < 2048; u += 512) {
    int blk = u >> 6, wi = (u & 63) * 8;
    int rl = (blk >> 2) * 16 + (wi >> 5);
    int cl = (blk & 3) * 32 + (wi & 31);
    int gi = i0 + rl, gj = j0 + cl;
    size_t go = ((size_t)(gi >> 4) * 128 + (gj >> 5)) * 512 + (gi & 15) * 32 + (gj & 31);
    *(int4*)&pb[go] = *(int4*)&ts[rl * 136 + cl];
  }
}

// ---------------------------------------------------------------------------
// K_pv: pam[c][i] = sum_j V[c][j] P[i][j]; fused epilogue:
// sa = tanh(gp * pam/(l*N) + x) -> sa_pk PK(512,4096) + saT_pk PK(4096,512).
// A = v_pk rows c, B = p_pk rows i, K = 4096 (128 k-steps, no inner barrier).
// ---------------------------------------------------------------------------
__global__ __launch_bounds__(512) void k_pv(
    const unsigned short* __restrict__ v_pk, const unsigned short* __restrict__ p_pk,
    const float* __restrict__ l_g, const float* __restrict__ x,
    const float* __restrict__ gamma_pam,
    unsigned short* __restrict__ sa_pk, unsigned short* __restrict__ saT_pk, int bbase) {
  const int z = blockIdx.z, b = bbase + z;
  const int c0 = blockIdx.y * 128, n0 = blockIdx.x * 128;
  const int t = threadIdx.x, wave = t >> 6, lane = t & 63;
  const int la = lane & 15, quad = lane >> 4;
  const int cw = wave & 1, nw = wave >> 1;
  const int lanelin = la * 32 + quad * 8;
  __shared__ unsigned short ts[128 * 136];

  const unsigned short* vb = v_pk + (size_t)b * C_ * N_;
  const unsigned short* pb = p_pk + (size_t)z * N_ * N_;

  v4f acc[4][2];
#pragma unroll
  for (int i = 0; i < 4; ++i)
#pragma unroll
    for (int j = 0; j < 2; ++j) acc[i][j] = (v4f){0.f, 0.f, 0.f, 0.f};

  const int ar16 = (c0 + cw * 64) >> 4;       // v_pk row-blocks (K=4096 -> 128 k32)
  const int br16 = (n0 + nw * 32) >> 4;       // p_pk row-blocks
#pragma unroll 4
  for (int s = 0; s < 128; ++s) {
    v8s b0 = ld8(&pb[((size_t)(br16 + 0) * 128 + s) * 512 + lanelin]);
    v8s b1 = ld8(&pb[((size_t)(br16 + 1) * 128 + s) * 512 + lanelin]);
#pragma unroll
    for (int ci = 0; ci < 4; ++ci) {
      v8s a = ld8(&vb[((size_t)(ar16 + ci) * 128 + s) * 512 + lanelin]);
      acc[ci][0] = mfma16(a, b0, acc[ci][0]);
      acc[ci][1] = mfma16(a, b1, acc[ci][1]);
    }
  }

  const float gpv = gamma_pam[0];
  float linv[2];
#pragma unroll
  for (int nj = 0; nj < 2; ++nj)
    linv[nj] = 1.0f / (l_g[(size_t)b * N_ + n0 + nw * 32 + nj * 16 + la] * (float)N_);

  // sa values -> stage [c][n]
#pragma unroll
  for (int ci = 0; ci < 4; ++ci)
#pragma unroll
    for (int nj = 0; nj < 2; ++nj)
#pragma unroll
      for (int r = 0; r < 4; ++r) {
        int cl = cw * 64 + ci * 16 + quad * 4 + r;
        int nl = nw * 32 + nj * 16 + la;
        float xv = x[((size_t)b * C_ + c0 + cl) * N_ + n0 + nl];
        float sv = tanhf(fmaf(gpv, acc[ci][nj][r] * linv[nj], xv));
        ts[cl * 136 + nl] = f2bf(sv);
      }
  __syncthreads();
  {
    unsigned short* dst = sa_pk + (size_t)b * C_ * N_;
#pragma unroll
    for (int u = t; u < 2048; u += 512) {
      int blk = u >> 6, wi = (u & 63) * 8;
      int rl = (blk >> 2) * 16 + (wi >> 5);
      int kl = (blk & 3) * 32 + (wi & 31);
      int gr = c0 + rl, gk = n0 + kl;
      size_t go = ((size_t)(gr >> 4) * 128 + (gk >> 5)) * 512 + (gr & 15) * 32 + (gk & 31);
      *(int4*)&dst[go] = *(int4*)&ts[rl * 136 + kl];
    }
  }
  __syncthreads();
  // transpose stage [n][c]
#pragma unroll
  for (int ci = 0; ci < 4; ++ci)
#pragma unroll
    for (int nj = 0; nj < 2; ++nj)
#pragma unroll
      for (int r = 0; r < 4; ++r) {
        int cl = cw * 64 + ci * 16 + quad * 4 + r;
        int nl = nw * 32 + nj * 16 + la;
        unsigned short us;
        // re-read from registers is cheaper than LDS round trip: recompute store
        // (value already in ts at [cl][nl]; read it back to avoid recompute)
        us = ts[cl * 136 + nl];
        // note: read-before-overwrite safe: we write [nl][cl] region after barrier below
        ts[nl * 136 + cl + (nl & 1) * 0] = us;  // plain transposed store
      }
  __syncthreads();
  {
    unsigned short* dst = saT_pk + (size_t)b * N_ * C_;
#pragma unroll
    for (int u = t; u < 2048; u += 512) {
      int blk = u >> 6, wi = (u & 63) * 8;
      int rl = (blk >> 2) * 16 + (wi >> 5);
      int kl = (blk & 3) * 32 + (wi & 31);
      int gr = n0 + rl, gk = c0 + kl;
      size_t go = ((size_t)(gr >> 4) * 16 + (gk >> 5)) * 512 + (gr & 15) * 32 + (gk & 31);
      *(int4*)&dst[go] = *(int4*)&ts[rl * 136 + kl];
    }
  }
}

// ---------------------------------------------------------------------------
// K_cam_e: e_part[ks][b][c][d] = scale * sum_n sa_c sa_d.  64x64 tile, ks4.
// ---------------------------------------------------------------------------
__global__ __launch_bounds__(256) void k_cam_e(const unsigned short* __restrict__ sa_pk,
                                               float* __restrict__ e_part) {
  const int b = blockIdx.z, ks = blockIdx.y;
  const int c0 = (blockIdx.x & 7) * 64, d0 = (blockIdx.x >> 3) * 64;
  const int t = threadIdx.x, wave = t >> 6, lane = t & 63;
  const int la = lane & 15, quad = lane >> 4;
  const int cw = wave & 1, dw = wave >> 1;
  const int lanelin = la * 32 + quad * 8;
  const unsigned short* sb = sa_pk + (size_t)b * C_ * N_;

  v4f acc[2][2];
#pragma unroll
  for (int i = 0; i < 2; ++i)
#pragma unroll
    for (int j = 0; j < 2; ++j) acc[i][j] = (v4f){0.f, 0.f, 0.f, 0.f};

  const int ar16 = (c0 + cw * 32) >> 4;
  const int br16 = (d0 + dw * 32) >> 4;
#pragma unroll 4
  for (int s = 0; s < 32; ++s) {
    const int k32 = ks * 32 + s;
    v8s a0 = ld8(&sb[((size_t)(ar16 + 0) * 128 + k32) * 512 + lanelin]);
    v8s a1 = ld8(&sb[((size_t)(ar16 + 1) * 128 + k32) * 512 + lanelin]);
    v8s b0 = ld8(&sb[((size_t)(br16 + 0) * 128 + k32) * 512 + lanelin]);
    v8s b1 = ld8(&sb[((size_t)(br16 + 1) * 128 + k32) * 512 + lanelin]);
    acc[0][0] = mfma16(a0, b0, acc[0][0]);
    acc[0][1] = mfma16(a0, b1, acc[0][1]);
    acc[1][0] = mfma16(a1, b0, acc[1][0]);
    acc[1][1] = mfma16(a1, b1, acc[1][1]);
  }
  float* ep = e_part + ((size_t)(ks * B_ + b)) * C_ * C_;
#pragma unroll
  for (int i = 0; i < 2; ++i)
#pragma unroll
    for (int j = 0; j < 2; ++j)
#pragma unroll
      for (int r = 0; r < 4; ++r) {
        int c = c0 + cw * 32 + i * 16 + quad * 4 + r;
        int d = d0 + dw * 32 + j * 16 + la;
        ep[(size_t)c * C_ + d] = acc[i][j][r] * SCALE_CAM;
      }
}

// ---------------------------------------------------------------------------
// K_cam_softmax: min-trick softmax over 4 parts -> attn_pk PK(512,512).
// ---------------------------------------------------------------------------
__global__ __launch_bounds__(64) void k_cam_softmax(const float* __restrict__ e_part,
                                                    unsigned short* __restrict__ attn_pk) {
  const int c = blockIdx.x, b = blockIdx.y, lane = threadIdx.x;
  size_t roff = ((size_t)b * C_ + c) * C_;
  float vals[8];
#pragma unroll
  for (int r = 0; r < 8; ++r) {
    int d = lane + r * 64;
    float s = 0.f;
#pragma unroll
    for (int p = 0; p < 4; ++p) s += e_part[(size_t)(p * B_) * C_ * C_ + roff + d];
    vals[r] = s;
  }
  float mn = vals[0];
#pragma unroll
  for (int r = 1; r < 8; ++r) mn = fminf(mn, vals[r]);
#pragma unroll
  for (int m = 32; m >= 1; m >>= 1) mn = fminf(mn, __shfl_xor(mn, m));
  float sum = 0.f;
#pragma unroll
  for (int r = 0; r < 8; ++r) { vals[r] = __expf(mn - vals[r]); sum += vals[r]; }
#pragma unroll
  for (int m = 32; m >= 1; m >>= 1) sum += __shfl_xor(sum, m);
  float sc = (1.0f / (float)C_) / sum;
  unsigned short* ab = attn_pk + (size_t)b * C_ * C_;
#pragma unroll
  for (int r = 0; r < 8; ++r) {
    int d = lane + r * 64;
    size_t go = ((size_t)(c >> 4) * 16 + (d >> 5)) * 512 + (c & 15) * 32 + (d & 31);
    ab[go] = f2bf(vals[r] * sc);
  }
}

// ---------------------------------------------------------------------------
// K_cam_out: out = gc * (attn @ sa) + sa.  128c x 128n tile, 512 thr.
// ---------------------------------------------------------------------------
__global__ __launch_bounds__(512) void k_cam_out(
    const unsigned short* __restrict__ attn_pk, const unsigned short* __restrict__ saT_pk,
    const unsigned short* __restrict__ sa_pk, const float* __restrict__ gamma_cam,
    float* __restrict__ out) {
  const int b = blockIdx.z, c0 = blockIdx.y * 128, n0 = blockIdx.x * 128;
  const int t = threadIdx.x, wave = t >> 6, lane = t & 63;
  const int la = lane & 15, quad = lane >> 4;
  const int cw = wave & 1, nw = wave >> 1;
  const int lanelin = la * 32 + quad * 8;
  const unsigned short* ab = attn_pk + (size_t)b * C_ * C_;
  const unsigned short* sTb = saT_pk + (size_t)b * N_ * C_;
  const unsigned short* sb = sa_pk + (size_t)b * C_ * N_;

  v4f acc[4][2];
#pragma unroll
  for (int i = 0; i < 4; ++i)
#pragma unroll
    for (int j = 0; j < 2; ++j) acc[i][j] = (v4f){0.f, 0.f, 0.f, 0.f};

  const int ar16 = (c0 + cw * 64) >> 4;
  const int br16 = (n0 + nw * 32) >> 4;
#pragma unroll 4
  for (int s = 0; s < 16; ++s) {
    v8s b0 = ld8(&sTb[((size_t)(br16 + 0) * 16 + s) * 512 + lanelin]);
    v8s b1 = ld8(&sTb[((size_t)(br16 + 1) * 16 + s) * 512 + lanelin]);
#pragma unroll
    for (int ci = 0; ci < 4; ++ci) {
      v8s a = ld8(&ab[((size_t)(ar16 + ci) * 16 + s) * 512 + lanelin]);
      acc[ci][0] = mfma16(a, b0, acc[ci][0]);
      acc[ci][1] = mfma16(a, b1, acc[ci][1]);
    }
  }
  const float gc = gamma_cam[0];
#pragma unroll
  for (int ci = 0; ci < 4; ++ci)
#pragma unroll
    for (int nj = 0; nj < 2; ++nj)
#pragma unroll
      for (int r = 0; r < 4; ++r) {
        int c = c0 + cw * 64 + ci * 16 + quad * 4 + r;
        int n = n0 + nw * 32 + nj * 16 + la;
        size_t pko = ((size_t)(c >> 4) * 128 + (n >> 5)) * 512 + (c & 15) * 32 + (n & 31);
        out[((size_t)b * C_ + c) * N_ + n] = fmaf(gc, acc[ci][nj][r], bf2f(sb[pko]));
      }
}

// ---------------------------------------------------------------------------
extern "C" void kernel_launch(void* const* d_in, const int* in_sizes, int n_in,
                              void* d_out, int out_size, void* d_ws, size_t ws_size,
                              hipStream_t stream) {
  const float* x  = (const float*)d_in[0];
  const float* wq = (const float*)d_in[1];
  const float* bq = (const float*)d_in[2];
  const float* wk = (const float*)d_in[3];
  const float* bk = (const float*)d_in[4];
  const float* wv = (const float*)d_in[5];
  const float* bv = (const float*)d_in[6];
  const float* gp = (const float*)d_in[7];
  const float* gc = (const float*)d_in[8];
  float* out = (float*)d_out;

  char* ws = (char*)d_ws;
  // Region map (total ~118.6 MB, same budget as R6):
  //  A 0        : x_pk (16.78M)  -> later sa_pk
  //  B 16.78M   : w_pk (1.05M)
  //  C 17.83M   : q_pk (8.39M)   -> later saT_pk (spans C+D, 16.78M)
  //  D 26.21M   : k_pk (8.39M)
  //  E 34.60M   : v_pk (16.78M)  -> later ep
  //  F 51.38M   : p_pk (64M, 2-batch) -> later at_pk (first 2.1M)
  //  G 118.49M  : l_g (64 KB)
  unsigned short* x_pk   = (unsigned short*)(ws);
  unsigned short* w_pk   = (unsigned short*)(ws + 16777216);
  unsigned short* q_pk   = (unsigned short*)(ws + 17825792);
  unsigned short* k_pk   = (unsigned short*)(ws + 26214400);
  unsigned short* v_pk   = (unsigned short*)(ws + 34603008);
  unsigned short* p_pk   = (unsigned short*)(ws + 51380224);
  float*          l_g    = (float*)(ws + 118489088);
  unsigned short* sa_pk  = (unsigned short*)(ws);              // reuse A
  unsigned short* saT_pk = (unsigned short*)(ws + 17825792);   // reuse C+D
  float*          ep     = (float*)(ws + 34603008);            // reuse E
  unsigned short* at_pk  = (unsigned short*)(ws + 51380224);   // reuse F

  k_xT<<<dim3(64, 8, B_), 256, 0, stream>>>(x, x_pk);
  k_wb<<<256, 256, 0, stream>>>(wq, wk, wv, w_pk);
  k_qkv<<<dim3(32, 8, B_), 512, 0, stream>>>(w_pk, x_pk, bq, bk, bv, q_pk, k_pk, v_pk);
  k_zl<<<16, 256, 0, stream>>>(l_g);
  for (int bp = 0; bp < 2; ++bp) {
    k_s<<<dim3(32, 32, 2), 512, 0, stream>>>(q_pk, k_pk, p_pk, l_g, bp * 2);
    k_pv<<<dim3(32, 4, 2), 512, 0, stream>>>(v_pk, p_pk, l_g, x, gp, sa_pk, saT_pk, bp * 2);
  }
  k_cam_e<<<dim3(64, 4, B_), 256, 0, stream>>>(sa_pk, ep);
  k_cam_softmax<<<dim3(C_, B_), 64, 0, stream>>>(ep, at_pk);
  k_cam_out<<<dim3(32, 4, B_), 512, 0, stream>>>(at_pk, saT_pk, sa_pk, gc, out);
}